// Round 12
// baseline (149.041 us; speedup 1.0000x reference)
//
#include <hip/hip_runtime.h>
#include <hip/hip_bf16.h>
#include <stdint.h>
#include <stddef.h>

// ---------------------------------------------------------------------------
// ResAttnBlock: GroupNorm -> QKV -> full spatial attention -> proj -> residual
// B=32, C=256, S=32 (P=1024 positions), 32 groups of 8 channels.
// ---------------------------------------------------------------------------

typedef float  f32x4  __attribute__((ext_vector_type(4)));
typedef __bf16 bf16x8 __attribute__((ext_vector_type(8)));
typedef __bf16 bf16x4 __attribute__((ext_vector_type(4)));

#define DEVI static __device__ __forceinline__

DEVI f32x4 mfma16(bf16x8 a, bf16x8 b, f32x4 c) {
  return __builtin_amdgcn_mfma_f32_16x16x32_bf16(a, b, c, 0, 0, 0);
}

DEVI f32x4 zero4() { f32x4 z = {0.f, 0.f, 0.f, 0.f}; return z; }

typedef const __attribute__((address_space(1))) void* gas_cvp;
typedef __attribute__((address_space(3))) void*       las_vp;

DEVI void gl_lds16(const __bf16* g, __bf16* l) {
  __builtin_amdgcn_global_load_lds((gas_cvp)g, (las_vp)l, 16, 0, 0);
}

#define WAIT_VM(N) asm volatile("s_waitcnt vmcnt(" #N ")" ::: "memory")
DEVI void bar() {
  asm volatile("" ::: "memory");
  __builtin_amdgcn_s_barrier();
  asm volatile("" ::: "memory");
}

// ---------------------------------------------------------------------------
// Kernel 0: convert weights to bf16
// ---------------------------------------------------------------------------
__global__ __launch_bounds__(256) void cvt_weights(
    const float* __restrict__ wa, const float* __restrict__ wp,
    __bf16* __restrict__ wab, __bf16* __restrict__ wpb) {
  const int i = blockIdx.x * 256 + threadIdx.x;
  if (i < 196608) {
    wab[i] = (__bf16)wa[i];
  } else {
    const int j = i - 196608;
    if (j < 65536) wpb[j] = (__bf16)wp[j];
  }
}

// ---------------------------------------------------------------------------
// Kernel 1: fused GroupNorm (stats + apply + transpose), single x pass.
// ---------------------------------------------------------------------------
__global__ __launch_bounds__(256) void gn_fused(
    const float* __restrict__ x, const float* __restrict__ gamma,
    const float* __restrict__ beta, __bf16* __restrict__ h) {
  __shared__ __align__(16) float xs[8192];
  __shared__ float redS[4], redSS[4];
  const int bg = blockIdx.x;           // b*32+g
  const int b = bg >> 5, g = bg & 31;
  const int tid = threadIdx.x;
  const float* base = x + (size_t)bg * 8192;
  float s = 0.f, ss = 0.f;
#pragma unroll
  for (int it = 0; it < 8; ++it) {
    const int i = it * 256 + tid;
    f32x4 v = *(const f32x4*)(base + i * 4);
    *(f32x4*)(xs + i * 4) = v;
    s  += v[0] + v[1] + v[2] + v[3];
    ss += v[0]*v[0] + v[1]*v[1] + v[2]*v[2] + v[3]*v[3];
  }
#pragma unroll
  for (int m = 1; m < 64; m <<= 1) {
    s  += __shfl_xor(s,  m, 64);
    ss += __shfl_xor(ss, m, 64);
  }
  const int lane = tid & 63, wave = tid >> 6;
  if (lane == 0) { redS[wave] = s; redSS[wave] = ss; }
  __syncthreads();
  const float S  = redS[0] + redS[1] + redS[2] + redS[3];
  const float SS = redSS[0] + redSS[1] + redSS[2] + redSS[3];
  const float mu = S * (1.f / 8192.f);
  const float rstd = rsqrtf(SS * (1.f / 8192.f) - mu * mu + 1e-5f);
  float ga[8], be[8];
#pragma unroll
  for (int j = 0; j < 8; ++j) {
    const int c = g * 8 + j;
    ga[j] = gamma[c] * rstd;
    be[j] = beta[c] - mu * ga[j];
  }
  __bf16* hb = h + ((size_t)b << 18) + g * 8;   // h[b][p][c]
#pragma unroll
  for (int it = 0; it < 4; ++it) {
    const int p = it * 256 + tid;
    bf16x8 o8;
#pragma unroll
    for (int j = 0; j < 8; ++j)
      o8[j] = (__bf16)(xs[j * 1024 + p] * ga[j] + be[j]);
    *(bf16x8*)(hb + ((size_t)p << 8)) = o8;
  }
}

// ---------------------------------------------------------------------------
// Shared GEMM core: C(128x128) = A(128xK=256) * Bt(128 rows x 256)^T
// ---------------------------------------------------------------------------
DEVI void gemm_core_k256(const __bf16* __restrict__ A0, const __bf16* __restrict__ B0,
                         __bf16* lA, __bf16* lB, int lane, int wave, f32x4 acc[4][4]) {
  const int wm = (wave >> 1) * 64;
  const int wn = (wave & 1) * 64;
  const int r15 = lane & 15, lg = lane >> 4;
#pragma unroll
  for (int i = 0; i < 4; ++i)
#pragma unroll
    for (int j = 0; j < 4; ++j) acc[i][j] = zero4();

  for (int ko = 0; ko < 4; ++ko) {
#pragma unroll
    for (int it = 0; it < 4; ++it) {
      const int q = wave * 256 + it * 64 + lane;
      const int row = q >> 3, c8 = q & 7;
      const int srcoff = row * 256 + ko * 64 + ((c8 ^ (row & 7)) << 3);
      gl_lds16(A0 + srcoff, lA + (size_t)(wave * 256 + it * 64) * 8);
      gl_lds16(B0 + srcoff, lB + (size_t)(wave * 256 + it * 64) * 8);
    }
    __syncthreads();
#pragma unroll
    for (int kk = 0; kk < 2; ++kk) {
      bf16x8 af[4], bfr[4];
#pragma unroll
      for (int i = 0; i < 4; ++i) {
        const int row = wm + i * 16 + r15;
        af[i] = *(const bf16x8*)((const char*)lA + row * 128 +
                                 (((kk * 4 + lg) ^ (row & 7)) << 4));
      }
#pragma unroll
      for (int j = 0; j < 4; ++j) {
        const int row = wn + j * 16 + r15;
        bfr[j] = *(const bf16x8*)((const char*)lB + row * 128 +
                                  (((kk * 4 + lg) ^ (row & 7)) << 4));
      }
#pragma unroll
      for (int i = 0; i < 4; ++i)
#pragma unroll
        for (int j = 0; j < 4; ++j) acc[i][j] = mfma16(af[i], bfr[j], acc[i][j]);
    }
    __syncthreads();
  }
}

// ---------------------------------------------------------------------------
// Kernel 3: QKV GEMM. h(32768x256) @ w_attn(768x256)^T + bias.
// ---------------------------------------------------------------------------
__global__ __launch_bounds__(256) void qkv_gemm(
    const __bf16* __restrict__ h, const __bf16* __restrict__ wab,
    const float* __restrict__ b_attn,
    __bf16* __restrict__ q, __bf16* __restrict__ k, __bf16* __restrict__ vt) {
  __shared__ __align__(16) __bf16 lA[128 * 64], lB[128 * 64];
  const int nt = blockIdx.x, mt = blockIdx.y;
  const int tid = threadIdx.x, lane = tid & 63, wave = tid >> 6;
  f32x4 acc[4][4];
  gemm_core_k256(h + (size_t)mt * 128 * 256, wab + (size_t)nt * 128 * 256,
                 lA, lB, lane, wave, acc);

  const int wm = (wave >> 1) * 64, wn = (wave & 1) * 64;
  const int r15 = lane & 15, lg = lane >> 4;
  const int sec = nt >> 1;  // 0=q, 1=k, 2=v
  const float QS = 0.0625f * 1.44269504088896340736f;  // (1/sqrt(256))*log2(e)
#pragma unroll
  for (int j = 0; j < 4; ++j) {
    const int ng = nt * 128 + wn + j * 16 + r15;
    const float bias = b_attn[ng];
    const int c = ng & 255;
#pragma unroll
    for (int i = 0; i < 4; ++i) {
      const int mbase = mt * 128 + wm + i * 16 + lg * 4;
      if (sec == 0) {
#pragma unroll
        for (int r = 0; r < 4; ++r)
          q[(size_t)(mbase + r) * 256 + c] = (__bf16)((acc[i][j][r] + bias) * QS);
      } else if (sec == 1) {
#pragma unroll
        for (int r = 0; r < 4; ++r)
          k[(size_t)(mbase + r) * 256 + c] = (__bf16)(acc[i][j][r] + bias);
      } else {
        const int b = mbase >> 10, p = mbase & 1023;
        bf16x4 pk;
#pragma unroll
        for (int r = 0; r < 4; ++r) pk[r] = (__bf16)(acc[i][j][r] + bias);
        *(bf16x4*)(vt + (((size_t)(b * 256 + c)) << 10) + p) = pk;
      }
    }
  }
}

// ---------------------------------------------------------------------------
// Kernel 4: flash attention, R7 structure + d-split PV.
// R7 model: LDS-port-bound, dominated by V-reads replicated 4x across waves
// (each wave streamed all 256 d). Here PV is split by d: P goes to a
// BLOCK-shared [64 q][64 kv] tile (8KB, row&7 swz) + per-tile rescale
// factors broadcast via LDS; each wave then computes its own 64-wide
// d-slice for all 64 q-rows -> V-reads/wave/iter 32 -> 8 (no replication).
// QK^T/softmax unchanged (wave owns 16 q-rows, Q in regs). Same 3-barrier
// counted-vmcnt schedule as R7. Grid 512 = 2 blocks/CU (74240B LDS).
// ---------------------------------------------------------------------------
__global__ __launch_bounds__(256, 1) void attn(
    const __bf16* __restrict__ q, const __bf16* __restrict__ k,
    const __bf16* __restrict__ vt, __bf16* __restrict__ o) {
  extern __shared__ __align__(16) char smem[];   // 74240 B
  // lK @0      [64 kv][256 k] 32KB (512B rows, swz)
  // lV @32768  [256 d][64 kv] 32KB (128B rows, swz)
  // P  @65536  [64 q][64 kv]  8KB  (128B rows, swz)
  // scl @73728 [64] f32; lfin @73984 [64] f32

  const int bid = blockIdx.x;
  const int xcd = bid & 7, sub = bid >> 3;       // sub 0..63
  const int b = xcd * 4 + (sub & 3);             // same-b blocks share an XCD
  const int qt = sub >> 2;                       // 0..15
  const int tid = threadIdx.x, lane = tid & 63, wave = tid >> 6;
  const int r15 = lane & 15, lg = lane >> 4, rs7 = r15 & 7;
  const int m0 = qt * 64;                        // block q-base
  char* lK = smem;
  char* lV = smem + 32768;
  char* P  = smem + 65536;
  float* sclb = (float*)(smem + 73728);
  float* lfin = (float*)(smem + 73984);

  const __bf16* kb = k  + ((size_t)b << 18);
  const __bf16* vb = vt + ((size_t)b << 18);

  // Q fragments for this wave's 16 q-rows (32 VGPR); B-operand layout
  const __bf16* qbp = q + (((size_t)(b * 1024 + m0 + wave * 16)) << 8);
  bf16x8 qf[8];
#pragma unroll
  for (int kc = 0; kc < 8; ++kc)
    qf[kc] = *(const bf16x8*)(qbp + ((size_t)r15) * 256 + kc * 32 + lg * 8);

  // O^T d-slice accumulator: po[df][qf][r] = O[q=qf*16+r15][d=wave*64+df*16+lg*4+r]
  f32x4 po[4][4];
#pragma unroll
  for (int df = 0; df < 4; ++df)
#pragma unroll
    for (int qf2 = 0; qf2 < 4; ++qf2) po[df][qf2] = zero4();
  float mrun = -1e30f, lrun = 0.f;   // for q-row (wave*16 + r15)

  // staging: 2048 16B-chunks per tile, 8 per thread, pre-swizzled source
  auto stageK = [&](int n0) {
    __bf16* dst = (__bf16*)lK;
#pragma unroll
    for (int it = 0; it < 8; ++it) {
      const int qch = it * 256 + tid;            // [64 rows][32 chunks]
      const int row = qch >> 5, c32 = qch & 31;
      gl_lds16(kb + (size_t)(n0 + row) * 256 + ((c32 ^ (row & 7)) << 3),
               dst + (size_t)(it * 256 + wave * 64) * 8);
    }
  };
  auto stageV = [&](int n0) {
    __bf16* dst = (__bf16*)lV;
#pragma unroll
    for (int it = 0; it < 8; ++it) {
      const int qch = it * 256 + tid;            // [256 rows][8 chunks]
      const int row = qch >> 3, c8 = qch & 7;
      gl_lds16(vb + ((size_t)row << 10) + n0 + ((c8 ^ (row & 7)) << 3),
               dst + (size_t)(it * 256 + wave * 64) * 8);
    }
  };

  stageK(0);
  stageV(0);

  for (int t = 0; t < 16; ++t) {
    const int n0n = (t + 1) * 64;
    WAIT_VM(8);     // own K(t) writes landed (V(t)'s 8 still in flight)
    bar();          // all waves: K(t) resident

    // ---- swapped QK^T: S^T(64x16) = K(64x256) x Q(16x256)^T ----
    f32x4 s[4];
#pragma unroll
    for (int j = 0; j < 4; ++j) s[j] = zero4();
    __builtin_amdgcn_s_setprio(1);
#pragma unroll
    for (int kc = 0; kc < 8; ++kc) {
      bf16x8 kf[4];
#pragma unroll
      for (int j = 0; j < 4; ++j)
        kf[j] = *(const bf16x8*)(lK + (j * 16 + r15) * 512 +
                                 (((kc * 4 + lg) ^ rs7) << 4));
#pragma unroll
      for (int j = 0; j < 4; ++j) s[j] = mfma16(kf[j], qf[kc], s[j]);
    }
    __builtin_amdgcn_s_setprio(0);
    // lane holds S[kv=j*16+lg*4+r][qrow = wave*16 + r15]
    // ---- online softmax: in-reg max/sum + 2 shfl steps ----
    float pmax = s[0][0];
#pragma unroll
    for (int j = 0; j < 4; ++j)
#pragma unroll
      for (int r = 0; r < 4; ++r) pmax = fmaxf(pmax, s[j][r]);
    pmax = fmaxf(pmax, __shfl_xor(pmax, 16, 64));
    pmax = fmaxf(pmax, __shfl_xor(pmax, 32, 64));
    float sclv = 1.f;
    if (!__all(pmax <= mrun + 8.f)) {   // defer-rescale: P bounded by 2^8
      const float mn = fmaxf(mrun, pmax);
      sclv = exp2f(mrun - mn);
      mrun = mn;
      lrun *= sclv;
    }
    float psum = 0.f;
    bf16x4 pk[4];
#pragma unroll
    for (int j = 0; j < 4; ++j)
#pragma unroll
      for (int r = 0; r < 4; ++r) {
        const float pv = exp2f(s[j][r] - mrun);
        psum += pv;
        pk[j][r] = (__bf16)pv;
      }
    psum += __shfl_xor(psum, 16, 64);
    psum += __shfl_xor(psum, 32, 64);
    lrun += psum;
    // ---- P -> block-shared LDS [64 q][64 kv] (128B rows, row&7 swz) ----
    {
      const int prow = wave * 16 + r15;          // prow&7 == rs7
#pragma unroll
      for (int j = 0; j < 4; ++j)
        *(bf16x4*)(P + prow * 128 + ((j * 32 + lg * 8) ^ (rs7 << 4))) = pk[j];
      if (lg == 0) sclb[prow] = sclv;
    }

    WAIT_VM(0);     // own V(t) writes landed (K(t+1) not yet issued)
    bar();          // all waves: V(t) + P + scl visible; done reading lK
    if (t < 15) stageK(n0n);   // overwrite lK, hides under PV

    // ---- rescale own d-slice columns by owning waves' scl ----
    {
      float sv[4];
#pragma unroll
      for (int qf2 = 0; qf2 < 4; ++qf2) sv[qf2] = sclb[qf2 * 16 + r15];
      if (!__all(sv[0] * sv[1] * sv[2] * sv[3] == 1.f)) {
#pragma unroll
        for (int df = 0; df < 4; ++df)
#pragma unroll
          for (int qf2 = 0; qf2 < 4; ++qf2) po[df][qf2] *= sv[qf2];
      }
    }
    // ---- d-split PV: O^T[64d-slice x 64q] += V^T[slice x 64kv] x P^T ----
    bf16x8 pb[4][2];
#pragma unroll
    for (int qf2 = 0; qf2 < 4; ++qf2)
#pragma unroll
      for (int kk = 0; kk < 2; ++kk)
        pb[qf2][kk] = *(const bf16x8*)(P + (qf2 * 16 + r15) * 128 +
                                       (((kk * 4 + lg) ^ rs7) << 4));
    __builtin_amdgcn_s_setprio(1);
#pragma unroll
    for (int df = 0; df < 4; ++df)
#pragma unroll
      for (int kk = 0; kk < 2; ++kk) {
        const int vrow = wave * 64 + df * 16 + r15;   // vrow&7 == rs7
        const bf16x8 vf = *(const bf16x8*)(lV + vrow * 128 +
                                           (((kk * 4 + lg) ^ rs7) << 4));
#pragma unroll
        for (int qf2 = 0; qf2 < 4; ++qf2)
          po[df][qf2] = mfma16(vf, pb[qf2][kk], po[df][qf2]);
      }
    __builtin_amdgcn_s_setprio(0);
    bar();          // all waves done reading lV + P
    if (t < 15) stageV(n0n);   // hides under next QK^T
  }

  // ---- epilogue: broadcast l, then O/l, bf16x4 stores ----
  if (lg == 0) lfin[wave * 16 + r15] = lrun;
  __syncthreads();
  float inv[4];
#pragma unroll
  for (int qf2 = 0; qf2 < 4; ++qf2) inv[qf2] = 1.f / lfin[qf2 * 16 + r15];
#pragma unroll
  for (int qf2 = 0; qf2 < 4; ++qf2) {
    __bf16* ob = o + (((size_t)(b * 1024 + m0 + qf2 * 16 + r15)) << 8) + wave * 64;
#pragma unroll
    for (int df = 0; df < 4; ++df) {
      bf16x4 tv;
#pragma unroll
      for (int r = 0; r < 4; ++r) tv[r] = (__bf16)(po[df][qf2][r] * inv[qf2]);
      *(bf16x4*)(ob + df * 16 + lg * 4) = tv;
    }
  }
}

// ---------------------------------------------------------------------------
// Kernel 5: proj GEMM + bias + residual, writes fp32 out in (B,C,S,S).
// ---------------------------------------------------------------------------
__global__ __launch_bounds__(256) void proj_gemm(
    const __bf16* __restrict__ o, const __bf16* __restrict__ wpb,
    const float* __restrict__ b_proj, const float* __restrict__ x,
    float* __restrict__ out) {
  __shared__ __align__(16) __bf16 lA[128 * 64], lB[128 * 64];
  const int nt = blockIdx.x, mt = blockIdx.y;
  const int tid = threadIdx.x, lane = tid & 63, wave = tid >> 6;
  f32x4 acc[4][4];
  gemm_core_k256(o + (size_t)mt * 128 * 256, wpb + (size_t)nt * 128 * 256,
                 lA, lB, lane, wave, acc);

  const int wm = (wave >> 1) * 64, wn = (wave & 1) * 64;
  const int r15 = lane & 15, lg = lane >> 4;
#pragma unroll
  for (int j = 0; j < 4; ++j) {
    const int c = nt * 128 + wn + j * 16 + r15;
    const float bias = b_proj[c];
#pragma unroll
    for (int i = 0; i < 4; ++i) {
      const int mbase = mt * 128 + wm + i * 16 + lg * 4;
      const int b = mbase >> 10, p = mbase & 1023;
      const size_t off = (((size_t)(b * 256 + c)) << 10) + p;
      f32x4 xv = *(const f32x4*)(x + off);
      f32x4 r = acc[i][j];
      r = r + xv;
      r = r + bias;
      *(f32x4*)(out + off) = r;
    }
  }
}

// ---------------------------------------------------------------------------
// Launcher
// ---------------------------------------------------------------------------
extern "C" void kernel_launch(void* const* d_in, const int* in_sizes, int n_in,
                              void* d_out, int out_size, void* d_ws, size_t ws_size,
                              hipStream_t stream) {
  const float* x      = (const float*)d_in[0];
  // d_in[1] = t_embd (unused by reference)
  const float* gamma  = (const float*)d_in[2];
  const float* beta   = (const float*)d_in[3];
  const float* w_attn = (const float*)d_in[4];
  const float* b_attn = (const float*)d_in[5];
  const float* w_proj = (const float*)d_in[6];
  const float* b_proj = (const float*)d_in[7];
  float* out = (float*)d_out;

  char* ws = (char*)d_ws;
  __bf16* h   = (__bf16*)(ws);                          // 16MB, reused as o
  __bf16* qb  = (__bf16*)(ws + ((size_t)16 << 20));     // 16MB
  __bf16* kb  = (__bf16*)(ws + ((size_t)32 << 20));     // 16MB
  __bf16* vtb = (__bf16*)(ws + ((size_t)48 << 20));     // 16MB, [B][C][P]
  __bf16* wab = (__bf16*)(ws + ((size_t)64 << 20));     // 384KB
  __bf16* wpb = wab + 196608;                           // 128KB

  cvt_weights<<<1024, 256, 0, stream>>>(w_attn, w_proj, wab, wpb);
  gn_fused<<<1024, 256, 0, stream>>>(x, gamma, beta, h);
  qkv_gemm<<<dim3(6, 256), 256, 0, stream>>>(h, wab, b_attn, qb, kb, vtb);
  attn<<<512, 256, 74240, stream>>>(qb, kb, vtb, h /* o reuses h */);
  proj_gemm<<<dim3(2, 256), 256, 0, stream>>>(h, wpb, b_proj, x, out);
}

// Round 13
// 134.240 us; speedup vs baseline: 1.1103x; 1.1103x over previous
//
#include <hip/hip_runtime.h>
#include <hip/hip_bf16.h>
#include <stdint.h>
#include <stddef.h>

// ---------------------------------------------------------------------------
// ResAttnBlock: GroupNorm -> QKV -> full spatial attention -> proj -> residual
// B=32, C=256, S=32 (P=1024 positions), 32 groups of 8 channels.
// ---------------------------------------------------------------------------

typedef float  f32x4  __attribute__((ext_vector_type(4)));
typedef __bf16 bf16x8 __attribute__((ext_vector_type(8)));
typedef __bf16 bf16x4 __attribute__((ext_vector_type(4)));

#define DEVI static __device__ __forceinline__

DEVI f32x4 mfma16(bf16x8 a, bf16x8 b, f32x4 c) {
  return __builtin_amdgcn_mfma_f32_16x16x32_bf16(a, b, c, 0, 0, 0);
}

DEVI f32x4 zero4() { f32x4 z = {0.f, 0.f, 0.f, 0.f}; return z; }

typedef const __attribute__((address_space(1))) void* gas_cvp;
typedef __attribute__((address_space(3))) void*       las_vp;

DEVI void gl_lds16(const __bf16* g, __bf16* l) {
  __builtin_amdgcn_global_load_lds((gas_cvp)g, (las_vp)l, 16, 0, 0);
}

#define WAIT_VM(N) asm volatile("s_waitcnt vmcnt(" #N ")" ::: "memory")
DEVI void bar() {
  asm volatile("" ::: "memory");
  __builtin_amdgcn_s_barrier();
  asm volatile("" ::: "memory");
}

// ---------------------------------------------------------------------------
// Kernel 1: fused GroupNorm (stats + apply + transpose) + weight conversion.
// Blocks 0..1023: one (b,g) group each. Blocks 1024..2047: cvt 256 weights
// floats each (wa 196608 + wp 65536 = 262144 = 1024 blocks x 256).
// ---------------------------------------------------------------------------
__global__ __launch_bounds__(256) void gn_fused(
    const float* __restrict__ x, const float* __restrict__ gamma,
    const float* __restrict__ beta, __bf16* __restrict__ h,
    const float* __restrict__ wa, const float* __restrict__ wp,
    __bf16* __restrict__ wab, __bf16* __restrict__ wpb) {
  __shared__ __align__(16) float xs[8192];
  __shared__ float redS[4], redSS[4];
  const int tid = threadIdx.x;
  if (blockIdx.x >= 1024) {            // weight-conversion blocks
    const int i = (blockIdx.x - 1024) * 256 + tid;
    if (i < 196608) wab[i] = (__bf16)wa[i];
    else wpb[i - 196608] = (__bf16)wp[i - 196608];
    return;
  }
  const int bg = blockIdx.x;           // b*32+g
  const int b = bg >> 5, g = bg & 31;
  const float* base = x + (size_t)bg * 8192;
  float s = 0.f, ss = 0.f;
#pragma unroll
  for (int it = 0; it < 8; ++it) {
    const int i = it * 256 + tid;
    f32x4 v = *(const f32x4*)(base + i * 4);
    *(f32x4*)(xs + i * 4) = v;
    s  += v[0] + v[1] + v[2] + v[3];
    ss += v[0]*v[0] + v[1]*v[1] + v[2]*v[2] + v[3]*v[3];
  }
#pragma unroll
  for (int m = 1; m < 64; m <<= 1) {
    s  += __shfl_xor(s,  m, 64);
    ss += __shfl_xor(ss, m, 64);
  }
  const int lane = tid & 63, wave = tid >> 6;
  if (lane == 0) { redS[wave] = s; redSS[wave] = ss; }
  __syncthreads();
  const float S  = redS[0] + redS[1] + redS[2] + redS[3];
  const float SS = redSS[0] + redSS[1] + redSS[2] + redSS[3];
  const float mu = S * (1.f / 8192.f);
  const float rstd = rsqrtf(SS * (1.f / 8192.f) - mu * mu + 1e-5f);
  float ga[8], be[8];
#pragma unroll
  for (int j = 0; j < 8; ++j) {
    const int c = g * 8 + j;
    ga[j] = gamma[c] * rstd;
    be[j] = beta[c] - mu * ga[j];
  }
  __bf16* hb = h + ((size_t)b << 18) + g * 8;   // h[b][p][c]
#pragma unroll
  for (int it = 0; it < 4; ++it) {
    const int p = it * 256 + tid;
    bf16x8 o8;
#pragma unroll
    for (int j = 0; j < 8; ++j)
      o8[j] = (__bf16)(xs[j * 1024 + p] * ga[j] + be[j]);
    *(bf16x8*)(hb + ((size_t)p << 8)) = o8;
  }
}

// ---------------------------------------------------------------------------
// Kernel 3: QKV GEMM, 128x256 tiles (nt=3: tile nt IS section q/k/v).
// 4 waves 2x2: each 64 rows x 128 cols = 4x8 frags (128 VGPR acc).
// 64 MFMA per wave per BK step -> half the barrier overhead per FLOP of
// the 128x128 version; A re-fetched 3x not 6x. LDS 48KB -> 2 blocks/CU.
// ---------------------------------------------------------------------------
__global__ __launch_bounds__(256) void qkv_gemm(
    const __bf16* __restrict__ h, const __bf16* __restrict__ wab,
    const float* __restrict__ b_attn,
    __bf16* __restrict__ q, __bf16* __restrict__ k, __bf16* __restrict__ vt) {
  __shared__ __align__(16) __bf16 lA[128 * 64], lB[256 * 64];
  const int nt = blockIdx.x, mt = blockIdx.y;
  const int tid = threadIdx.x, lane = tid & 63, wave = tid >> 6;
  const int wm = (wave >> 1) * 64, wn = (wave & 1) * 128;
  const int r15 = lane & 15, lg = lane >> 4;
  const __bf16* A0 = h + (size_t)mt * 128 * 256;
  const __bf16* B0 = wab + (size_t)nt * 256 * 256;

  f32x4 acc[4][8];
#pragma unroll
  for (int i = 0; i < 4; ++i)
#pragma unroll
    for (int j = 0; j < 8; ++j) acc[i][j] = zero4();

  for (int ko = 0; ko < 4; ++ko) {
    // stage A [128][64]: 1024 chunks, 4/thread
#pragma unroll
    for (int it = 0; it < 4; ++it) {
      const int q8 = it * 256 + tid;
      const int row = q8 >> 3, c8 = q8 & 7;
      gl_lds16(A0 + row * 256 + ko * 64 + ((c8 ^ (row & 7)) << 3),
               lA + (size_t)(it * 256 + wave * 64) * 8);
    }
    // stage B [256][64]: 2048 chunks, 8/thread
#pragma unroll
    for (int it = 0; it < 8; ++it) {
      const int q8 = it * 256 + tid;
      const int row = q8 >> 3, c8 = q8 & 7;
      gl_lds16(B0 + row * 256 + ko * 64 + ((c8 ^ (row & 7)) << 3),
               lB + (size_t)(it * 256 + wave * 64) * 8);
    }
    __syncthreads();
#pragma unroll
    for (int kk = 0; kk < 2; ++kk) {
      bf16x8 af[4], bfr[8];
#pragma unroll
      for (int i = 0; i < 4; ++i) {
        const int row = wm + i * 16 + r15;
        af[i] = *(const bf16x8*)((const char*)lA + row * 128 +
                                 (((kk * 4 + lg) ^ (row & 7)) << 4));
      }
#pragma unroll
      for (int j = 0; j < 8; ++j) {
        const int row = wn + j * 16 + r15;
        bfr[j] = *(const bf16x8*)((const char*)lB + row * 128 +
                                  (((kk * 4 + lg) ^ (row & 7)) << 4));
      }
#pragma unroll
      for (int i = 0; i < 4; ++i)
#pragma unroll
        for (int j = 0; j < 8; ++j) acc[i][j] = mfma16(af[i], bfr[j], acc[i][j]);
    }
    __syncthreads();
  }

  const float QS = 0.0625f * 1.44269504088896340736f;  // (1/sqrt(256))*log2(e)
#pragma unroll
  for (int j = 0; j < 8; ++j) {
    const int c = wn + j * 16 + r15;               // 0..255 within section
    const float bias = b_attn[nt * 256 + c];
#pragma unroll
    for (int i = 0; i < 4; ++i) {
      const int mbase = mt * 128 + wm + i * 16 + lg * 4;
      if (nt == 0) {
#pragma unroll
        for (int r = 0; r < 4; ++r)
          q[(size_t)(mbase + r) * 256 + c] = (__bf16)((acc[i][j][r] + bias) * QS);
      } else if (nt == 1) {
#pragma unroll
        for (int r = 0; r < 4; ++r)
          k[(size_t)(mbase + r) * 256 + c] = (__bf16)(acc[i][j][r] + bias);
      } else {
        const int b = mbase >> 10, p = mbase & 1023;
        bf16x4 pk;
#pragma unroll
        for (int r = 0; r < 4; ++r) pk[r] = (__bf16)(acc[i][j][r] + bias);
        *(bf16x4*)(vt + (((size_t)(b * 256 + c)) << 10) + p) = pk;
      }
    }
  }
}

// ---------------------------------------------------------------------------
// Kernel 4: flash attention — R7 VERBATIM (best measured: 61.6us).
// Grid 512, 4 waves x 16 q-rows, 72KB LDS -> 2 independent blocks/CU.
// Single-buffered K/V, counted-vmcnt 3-barrier schedule, swapped QK^T/PV,
// in-reg softmax, defer-rescale, setprio. m=32 & d-split variants all
// refuted (R6/R8/R9/R10/R12): VGPR>128 halves measured occupancy.
// ---------------------------------------------------------------------------
__global__ __launch_bounds__(256, 2) void attn(
    const __bf16* __restrict__ q, const __bf16* __restrict__ k,
    const __bf16* __restrict__ vt, __bf16* __restrict__ o) {
  extern __shared__ __align__(16) char smem[];   // 73728 B

  const int bid = blockIdx.x;
  const int xcd = bid & 7, sub = bid >> 3;       // sub 0..63
  const int b = xcd * 4 + (sub & 3);             // same-b blocks share an XCD
  const int qt = sub >> 2;                       // 0..15
  const int tid = threadIdx.x, lane = tid & 63, wave = tid >> 6;
  const int r15 = lane & 15, lg = lane >> 4, rs7 = r15 & 7;
  const int m0 = qt * 64 + wave * 16;
  char* P = smem + 65536 + wave * 2048;

  const __bf16* kb = k  + ((size_t)b << 18);
  const __bf16* vb = vt + ((size_t)b << 18);

  const __bf16* qb = q + (((size_t)(b * 1024 + m0)) << 8);
  bf16x8 qf[8];
#pragma unroll
  for (int kc = 0; kc < 8; ++kc)
    qf[kc] = *(const bf16x8*)(qb + ((size_t)r15) * 256 + kc * 32 + lg * 8);

  f32x4 po[16];   // O^T: po[df][r] = O[q=r15][d=df*16+lg*4+r]
#pragma unroll
  for (int d = 0; d < 16; ++d) po[d] = zero4();
  float mrun = -1e30f, lrun = 0.f;

  auto stageK = [&](int n0) {
    __bf16* dst = (__bf16*)smem;
#pragma unroll
    for (int it = 0; it < 8; ++it) {
      const int qch = it * 256 + tid;            // [64 rows][32 chunks]
      const int row = qch >> 5, c32 = qch & 31;
      gl_lds16(kb + (size_t)(n0 + row) * 256 + ((c32 ^ (row & 7)) << 3),
               dst + (size_t)(it * 256 + wave * 64) * 8);
    }
  };
  auto stageV = [&](int n0) {
    __bf16* dst = (__bf16*)(smem + 32768);
#pragma unroll
    for (int it = 0; it < 8; ++it) {
      const int qch = it * 256 + tid;            // [256 rows][8 chunks]
      const int row = qch >> 3, c8 = qch & 7;
      gl_lds16(vb + ((size_t)row << 10) + n0 + ((c8 ^ (row & 7)) << 3),
               dst + (size_t)(it * 256 + wave * 64) * 8);
    }
  };

  stageK(0);
  stageV(0);

  const char* lK = (const char*)smem;
  const char* lV = (const char*)smem + 32768;

  for (int kv = 0; kv < 16; ++kv) {
    WAIT_VM(8);
    bar();          // all waves: K(kv) resident

    // ---- swapped QK^T: S^T(64x16) = K(64x256) x Q(16x256)^T ----
    f32x4 s[4];
#pragma unroll
    for (int j = 0; j < 4; ++j) s[j] = zero4();
    __builtin_amdgcn_s_setprio(1);
#pragma unroll
    for (int kc = 0; kc < 8; ++kc) {
      bf16x8 kf[4];
#pragma unroll
      for (int j = 0; j < 4; ++j)
        kf[j] = *(const bf16x8*)(lK + (j * 16 + r15) * 512 +
                                 (((kc * 4 + lg) ^ rs7) << 4));
#pragma unroll
      for (int j = 0; j < 4; ++j) s[j] = mfma16(kf[j], qf[kc], s[j]);
    }
    __builtin_amdgcn_s_setprio(0);
    // ---- online softmax ----
    float pmax = s[0][0];
#pragma unroll
    for (int j = 0; j < 4; ++j)
#pragma unroll
      for (int r = 0; r < 4; ++r) pmax = fmaxf(pmax, s[j][r]);
    pmax = fmaxf(pmax, __shfl_xor(pmax, 16, 64));
    pmax = fmaxf(pmax, __shfl_xor(pmax, 32, 64));
    if (!__all(pmax <= mrun + 8.f)) {
      const float mn = fmaxf(mrun, pmax);
      const float scl = exp2f(mrun - mn);
      mrun = mn;
      lrun *= scl;
#pragma unroll
      for (int d = 0; d < 16; ++d) po[d] *= scl;
    }
    float psum = 0.f;
    bf16x4 pk[4];
#pragma unroll
    for (int j = 0; j < 4; ++j)
#pragma unroll
      for (int r = 0; r < 4; ++r) {
        const float pv = exp2f(s[j][r] - mrun);
        psum += pv;
        pk[j][r] = (__bf16)pv;
      }
    psum += __shfl_xor(psum, 16, 64);
    psum += __shfl_xor(psum, 32, 64);
    lrun += psum;
#pragma unroll
    for (int j = 0; j < 4; ++j)
      *(bf16x4*)(P + r15 * 128 + ((j * 32 + lg * 8) ^ (rs7 << 4))) = pk[j];

    WAIT_VM(0);
    bar();          // V(kv) resident; done reading lK
    if (kv < 15) stageK((kv + 1) * 64);

    // ---- swapped PV: O^T(256x16) += V^T(256x64) x P(16x64)^T ----
    __builtin_amdgcn_s_setprio(1);
#pragma unroll
    for (int kk = 0; kk < 2; ++kk) {
      const bf16x8 pb =
          *(const bf16x8*)(P + r15 * 128 + (((kk * 4 + lg) ^ rs7) << 4));
#pragma unroll
      for (int df = 0; df < 16; ++df) {
        const bf16x8 vf = *(const bf16x8*)(lV + (df * 16 + r15) * 128 +
                                           (((kk * 4 + lg) ^ rs7) << 4));
        po[df] = mfma16(vf, pb, po[df]);
      }
    }
    __builtin_amdgcn_s_setprio(0);
    bar();          // done reading lV
    if (kv < 15) stageV((kv + 1) * 64);
  }
  const float inv = 1.f / lrun;
  __bf16* ob = o + (((size_t)(b * 1024 + m0 + r15)) << 8);
#pragma unroll
  for (int df = 0; df < 16; ++df) {
    bf16x4 t;
#pragma unroll
    for (int r = 0; r < 4; ++r) t[r] = (__bf16)(po[df][r] * inv);
    *(bf16x4*)(ob + df * 16 + lg * 4) = t;
  }
}

// ---------------------------------------------------------------------------
// Kernel 5: proj GEMM + bias + residual (128x128 tiles, BK=64 core).
// ---------------------------------------------------------------------------
DEVI void gemm_core_k256(const __bf16* __restrict__ A0, const __bf16* __restrict__ B0,
                         __bf16* lA, __bf16* lB, int lane, int wave, f32x4 acc[4][4]) {
  const int wm = (wave >> 1) * 64;
  const int wn = (wave & 1) * 64;
  const int r15 = lane & 15, lg = lane >> 4;
#pragma unroll
  for (int i = 0; i < 4; ++i)
#pragma unroll
    for (int j = 0; j < 4; ++j) acc[i][j] = zero4();

  for (int ko = 0; ko < 4; ++ko) {
#pragma unroll
    for (int it = 0; it < 4; ++it) {
      const int q = wave * 256 + it * 64 + lane;
      const int row = q >> 3, c8 = q & 7;
      const int srcoff = row * 256 + ko * 64 + ((c8 ^ (row & 7)) << 3);
      gl_lds16(A0 + srcoff, lA + (size_t)(wave * 256 + it * 64) * 8);
      gl_lds16(B0 + srcoff, lB + (size_t)(wave * 256 + it * 64) * 8);
    }
    __syncthreads();
#pragma unroll
    for (int kk = 0; kk < 2; ++kk) {
      bf16x8 af[4], bfr[4];
#pragma unroll
      for (int i = 0; i < 4; ++i) {
        const int row = wm + i * 16 + r15;
        af[i] = *(const bf16x8*)((const char*)lA + row * 128 +
                                 (((kk * 4 + lg) ^ (row & 7)) << 4));
      }
#pragma unroll
      for (int j = 0; j < 4; ++j) {
        const int row = wn + j * 16 + r15;
        bfr[j] = *(const bf16x8*)((const char*)lB + row * 128 +
                                  (((kk * 4 + lg) ^ (row & 7)) << 4));
      }
#pragma unroll
      for (int i = 0; i < 4; ++i)
#pragma unroll
        for (int j = 0; j < 4; ++j) acc[i][j] = mfma16(af[i], bfr[j], acc[i][j]);
    }
    __syncthreads();
  }
}

__global__ __launch_bounds__(256) void proj_gemm(
    const __bf16* __restrict__ o, const __bf16* __restrict__ wpb,
    const float* __restrict__ b_proj, const float* __restrict__ x,
    float* __restrict__ out) {
  __shared__ __align__(16) __bf16 lA[128 * 64], lB[128 * 64];
  const int nt = blockIdx.x, mt = blockIdx.y;
  const int tid = threadIdx.x, lane = tid & 63, wave = tid >> 6;
  f32x4 acc[4][4];
  gemm_core_k256(o + (size_t)mt * 128 * 256, wpb + (size_t)nt * 128 * 256,
                 lA, lB, lane, wave, acc);

  const int wm = (wave >> 1) * 64, wn = (wave & 1) * 64;
  const int r15 = lane & 15, lg = lane >> 4;
#pragma unroll
  for (int j = 0; j < 4; ++j) {
    const int c = nt * 128 + wn + j * 16 + r15;
    const float bias = b_proj[c];
#pragma unroll
    for (int i = 0; i < 4; ++i) {
      const int mbase = mt * 128 + wm + i * 16 + lg * 4;
      const int b = mbase >> 10, p = mbase & 1023;
      const size_t off = (((size_t)(b * 256 + c)) << 10) + p;
      f32x4 xv = *(const f32x4*)(x + off);
      f32x4 r = acc[i][j];
      r = r + xv;
      r = r + bias;
      *(f32x4*)(out + off) = r;
    }
  }
}

// ---------------------------------------------------------------------------
// Launcher
// ---------------------------------------------------------------------------
extern "C" void kernel_launch(void* const* d_in, const int* in_sizes, int n_in,
                              void* d_out, int out_size, void* d_ws, size_t ws_size,
                              hipStream_t stream) {
  const float* x      = (const float*)d_in[0];
  // d_in[1] = t_embd (unused by reference)
  const float* gamma  = (const float*)d_in[2];
  const float* beta   = (const float*)d_in[3];
  const float* w_attn = (const float*)d_in[4];
  const float* b_attn = (const float*)d_in[5];
  const float* w_proj = (const float*)d_in[6];
  const float* b_proj = (const float*)d_in[7];
  float* out = (float*)d_out;

  char* ws = (char*)d_ws;
  __bf16* h   = (__bf16*)(ws);                          // 16MB, reused as o
  __bf16* qb  = (__bf16*)(ws + ((size_t)16 << 20));     // 16MB
  __bf16* kb  = (__bf16*)(ws + ((size_t)32 << 20));     // 16MB
  __bf16* vtb = (__bf16*)(ws + ((size_t)48 << 20));     // 16MB, [B][C][P]
  __bf16* wab = (__bf16*)(ws + ((size_t)64 << 20));     // 384KB
  __bf16* wpb = wab + 196608;                           // 128KB

  gn_fused<<<2048, 256, 0, stream>>>(x, gamma, beta, h, w_attn, w_proj, wab, wpb);
  qkv_gemm<<<dim3(3, 256), 256, 0, stream>>>(h, wab, b_attn, qb, kb, vtb);
  attn<<<512, 256, 73728, stream>>>(qb, kb, vtb, h /* o reuses h */);
  proj_gemm<<<dim3(2, 256), 256, 0, stream>>>(h, wpb, b_proj, x, out);
}

// Round 14
// 129.819 us; speedup vs baseline: 1.1481x; 1.0341x over previous
//
#include <hip/hip_runtime.h>
#include <hip/hip_bf16.h>
#include <stdint.h>
#include <stddef.h>

// ---------------------------------------------------------------------------
// ResAttnBlock: GroupNorm -> QKV -> full spatial attention -> proj -> residual
// B=32, C=256, S=32 (P=1024 positions), 32 groups of 8 channels.
// ---------------------------------------------------------------------------

typedef float  f32x4  __attribute__((ext_vector_type(4)));
typedef __bf16 bf16x8 __attribute__((ext_vector_type(8)));
typedef __bf16 bf16x4 __attribute__((ext_vector_type(4)));

#define DEVI static __device__ __forceinline__

DEVI f32x4 mfma16(bf16x8 a, bf16x8 b, f32x4 c) {
  return __builtin_amdgcn_mfma_f32_16x16x32_bf16(a, b, c, 0, 0, 0);
}

DEVI f32x4 zero4() { f32x4 z = {0.f, 0.f, 0.f, 0.f}; return z; }

typedef const __attribute__((address_space(1))) void* gas_cvp;
typedef __attribute__((address_space(3))) void*       las_vp;

DEVI void gl_lds16(const __bf16* g, __bf16* l) {
  __builtin_amdgcn_global_load_lds((gas_cvp)g, (las_vp)l, 16, 0, 0);
}

#define WAIT_VM(N) asm volatile("s_waitcnt vmcnt(" #N ")" ::: "memory")
DEVI void bar() {
  asm volatile("" ::: "memory");
  __builtin_amdgcn_s_barrier();
  asm volatile("" ::: "memory");
}

// ---------------------------------------------------------------------------
// Kernel 1: fused GroupNorm (stats + apply + transpose) + weight conversion.
// Blocks 0..1023: one (b,g) group each. Blocks 1024..2047: cvt 256 weight
// floats each (wa 196608 + wp 65536 = 262144 = 1024 blocks x 256).
// ---------------------------------------------------------------------------
__global__ __launch_bounds__(256) void gn_fused(
    const float* __restrict__ x, const float* __restrict__ gamma,
    const float* __restrict__ beta, __bf16* __restrict__ h,
    const float* __restrict__ wa, const float* __restrict__ wp,
    __bf16* __restrict__ wab, __bf16* __restrict__ wpb) {
  __shared__ __align__(16) float xs[8192];
  __shared__ float redS[4], redSS[4];
  const int tid = threadIdx.x;
  if (blockIdx.x >= 1024) {            // weight-conversion blocks
    const int i = (blockIdx.x - 1024) * 256 + tid;
    if (i < 196608) wab[i] = (__bf16)wa[i];
    else wpb[i - 196608] = (__bf16)wp[i - 196608];
    return;
  }
  const int bg = blockIdx.x;           // b*32+g
  const int b = bg >> 5, g = bg & 31;
  const float* base = x + (size_t)bg * 8192;
  float s = 0.f, ss = 0.f;
#pragma unroll
  for (int it = 0; it < 8; ++it) {
    const int i = it * 256 + tid;
    f32x4 v = *(const f32x4*)(base + i * 4);
    *(f32x4*)(xs + i * 4) = v;
    s  += v[0] + v[1] + v[2] + v[3];
    ss += v[0]*v[0] + v[1]*v[1] + v[2]*v[2] + v[3]*v[3];
  }
#pragma unroll
  for (int m = 1; m < 64; m <<= 1) {
    s  += __shfl_xor(s,  m, 64);
    ss += __shfl_xor(ss, m, 64);
  }
  const int lane = tid & 63, wave = tid >> 6;
  if (lane == 0) { redS[wave] = s; redSS[wave] = ss; }
  __syncthreads();
  const float S  = redS[0] + redS[1] + redS[2] + redS[3];
  const float SS = redSS[0] + redSS[1] + redSS[2] + redSS[3];
  const float mu = S * (1.f / 8192.f);
  const float rstd = rsqrtf(SS * (1.f / 8192.f) - mu * mu + 1e-5f);
  float ga[8], be[8];
#pragma unroll
  for (int j = 0; j < 8; ++j) {
    const int c = g * 8 + j;
    ga[j] = gamma[c] * rstd;
    be[j] = beta[c] - mu * ga[j];
  }
  __bf16* hb = h + ((size_t)b << 18) + g * 8;   // h[b][p][c]
#pragma unroll
  for (int it = 0; it < 4; ++it) {
    const int p = it * 256 + tid;
    bf16x8 o8;
#pragma unroll
    for (int j = 0; j < 8; ++j)
      o8[j] = (__bf16)(xs[j * 1024 + p] * ga[j] + be[j]);
    *(bf16x8*)(hb + ((size_t)p << 8)) = o8;
  }
}

// ---------------------------------------------------------------------------
// Shared GEMM core: C(128x128) = A(128xK=256) * Bt(128 rows x 256)^T
// 4 waves (2x2), each 64x64 = 4x4 frags. BK=64, 4 k-outer steps.
// ---------------------------------------------------------------------------
DEVI void gemm_core_k256(const __bf16* __restrict__ A0, const __bf16* __restrict__ B0,
                         __bf16* lA, __bf16* lB, int lane, int wave, f32x4 acc[4][4]) {
  const int wm = (wave >> 1) * 64;
  const int wn = (wave & 1) * 64;
  const int r15 = lane & 15, lg = lane >> 4;
#pragma unroll
  for (int i = 0; i < 4; ++i)
#pragma unroll
    for (int j = 0; j < 4; ++j) acc[i][j] = zero4();

  for (int ko = 0; ko < 4; ++ko) {
#pragma unroll
    for (int it = 0; it < 4; ++it) {
      const int q = wave * 256 + it * 64 + lane;
      const int row = q >> 3, c8 = q & 7;
      const int srcoff = row * 256 + ko * 64 + ((c8 ^ (row & 7)) << 3);
      gl_lds16(A0 + srcoff, lA + (size_t)(wave * 256 + it * 64) * 8);
      gl_lds16(B0 + srcoff, lB + (size_t)(wave * 256 + it * 64) * 8);
    }
    __syncthreads();
#pragma unroll
    for (int kk = 0; kk < 2; ++kk) {
      bf16x8 af[4], bfr[4];
#pragma unroll
      for (int i = 0; i < 4; ++i) {
        const int row = wm + i * 16 + r15;
        af[i] = *(const bf16x8*)((const char*)lA + row * 128 +
                                 (((kk * 4 + lg) ^ (row & 7)) << 4));
      }
#pragma unroll
      for (int j = 0; j < 4; ++j) {
        const int row = wn + j * 16 + r15;
        bfr[j] = *(const bf16x8*)((const char*)lB + row * 128 +
                                  (((kk * 4 + lg) ^ (row & 7)) << 4));
      }
#pragma unroll
      for (int i = 0; i < 4; ++i)
#pragma unroll
        for (int j = 0; j < 4; ++j) acc[i][j] = mfma16(af[i], bfr[j], acc[i][j]);
    }
    __syncthreads();
  }
}

// ---------------------------------------------------------------------------
// Kernel 3: QKV GEMM, 128x128 tiles (R7-proven), XCD-affine flattened grid:
// xcd = bid&7 owns a contiguous 32-mt band; nt varies fastest so the 6
// blocks sharing an A-panel (h rows) run on the SAME XCD's L2.
// ---------------------------------------------------------------------------
__global__ __launch_bounds__(256) void qkv_gemm(
    const __bf16* __restrict__ h, const __bf16* __restrict__ wab,
    const float* __restrict__ b_attn,
    __bf16* __restrict__ q, __bf16* __restrict__ k, __bf16* __restrict__ vt) {
  __shared__ __align__(16) __bf16 lA[128 * 64], lB[128 * 64];
  const int bid = blockIdx.x;              // 0..1535
  const int xcd = bid & 7, i2 = bid >> 3;  // i2 0..191
  const int nt = i2 % 6;
  const int mt = xcd * 32 + i2 / 6;        // 32 mt per XCD
  const int tid = threadIdx.x, lane = tid & 63, wave = tid >> 6;
  f32x4 acc[4][4];
  gemm_core_k256(h + (size_t)mt * 128 * 256, wab + (size_t)nt * 128 * 256,
                 lA, lB, lane, wave, acc);

  const int wm = (wave >> 1) * 64, wn = (wave & 1) * 64;
  const int r15 = lane & 15, lg = lane >> 4;
  const int sec = nt >> 1;  // 0=q, 1=k, 2=v
  const float QS = 0.0625f * 1.44269504088896340736f;  // (1/sqrt(256))*log2(e)
#pragma unroll
  for (int j = 0; j < 4; ++j) {
    const int ng = nt * 128 + wn + j * 16 + r15;
    const float bias = b_attn[ng];
    const int c = ng & 255;
#pragma unroll
    for (int i = 0; i < 4; ++i) {
      const int mbase = mt * 128 + wm + i * 16 + lg * 4;
      if (sec == 0) {
#pragma unroll
        for (int r = 0; r < 4; ++r)
          q[(size_t)(mbase + r) * 256 + c] = (__bf16)((acc[i][j][r] + bias) * QS);
      } else if (sec == 1) {
#pragma unroll
        for (int r = 0; r < 4; ++r)
          k[(size_t)(mbase + r) * 256 + c] = (__bf16)(acc[i][j][r] + bias);
      } else {
        const int b = mbase >> 10, p = mbase & 1023;
        bf16x4 pk;
#pragma unroll
        for (int r = 0; r < 4; ++r) pk[r] = (__bf16)(acc[i][j][r] + bias);
        *(bf16x4*)(vt + (((size_t)(b * 256 + c)) << 10) + p) = pk;
      }
    }
  }
}

// ---------------------------------------------------------------------------
// Kernel 4: flash attention — R7 VERBATIM (converged: 61.5us +/- 0.5).
// Grid 512, 4 waves x 16 q-rows, 72KB LDS -> 2 independent blocks/CU.
// Single-buffered K/V, counted-vmcnt 3-barrier schedule, swapped QK^T/PV,
// in-reg softmax, defer-rescale, setprio.
// ---------------------------------------------------------------------------
__global__ __launch_bounds__(256, 2) void attn(
    const __bf16* __restrict__ q, const __bf16* __restrict__ k,
    const __bf16* __restrict__ vt, __bf16* __restrict__ o) {
  extern __shared__ __align__(16) char smem[];   // 73728 B

  const int bid = blockIdx.x;
  const int xcd = bid & 7, sub = bid >> 3;       // sub 0..63
  const int b = xcd * 4 + (sub & 3);             // same-b blocks share an XCD
  const int qt = sub >> 2;                       // 0..15
  const int tid = threadIdx.x, lane = tid & 63, wave = tid >> 6;
  const int r15 = lane & 15, lg = lane >> 4, rs7 = r15 & 7;
  const int m0 = qt * 64 + wave * 16;
  char* P = smem + 65536 + wave * 2048;

  const __bf16* kb = k  + ((size_t)b << 18);
  const __bf16* vb = vt + ((size_t)b << 18);

  const __bf16* qb = q + (((size_t)(b * 1024 + m0)) << 8);
  bf16x8 qf[8];
#pragma unroll
  for (int kc = 0; kc < 8; ++kc)
    qf[kc] = *(const bf16x8*)(qb + ((size_t)r15) * 256 + kc * 32 + lg * 8);

  f32x4 po[16];   // O^T: po[df][r] = O[q=r15][d=df*16+lg*4+r]
#pragma unroll
  for (int d = 0; d < 16; ++d) po[d] = zero4();
  float mrun = -1e30f, lrun = 0.f;

  auto stageK = [&](int n0) {
    __bf16* dst = (__bf16*)smem;
#pragma unroll
    for (int it = 0; it < 8; ++it) {
      const int qch = it * 256 + tid;            // [64 rows][32 chunks]
      const int row = qch >> 5, c32 = qch & 31;
      gl_lds16(kb + (size_t)(n0 + row) * 256 + ((c32 ^ (row & 7)) << 3),
               dst + (size_t)(it * 256 + wave * 64) * 8);
    }
  };
  auto stageV = [&](int n0) {
    __bf16* dst = (__bf16*)(smem + 32768);
#pragma unroll
    for (int it = 0; it < 8; ++it) {
      const int qch = it * 256 + tid;            // [256 rows][8 chunks]
      const int row = qch >> 3, c8 = qch & 7;
      gl_lds16(vb + ((size_t)row << 10) + n0 + ((c8 ^ (row & 7)) << 3),
               dst + (size_t)(it * 256 + wave * 64) * 8);
    }
  };

  stageK(0);
  stageV(0);

  const char* lK = (const char*)smem;
  const char* lV = (const char*)smem + 32768;

  for (int kv = 0; kv < 16; ++kv) {
    WAIT_VM(8);
    bar();          // all waves: K(kv) resident

    // ---- swapped QK^T: S^T(64x16) = K(64x256) x Q(16x256)^T ----
    f32x4 s[4];
#pragma unroll
    for (int j = 0; j < 4; ++j) s[j] = zero4();
    __builtin_amdgcn_s_setprio(1);
#pragma unroll
    for (int kc = 0; kc < 8; ++kc) {
      bf16x8 kf[4];
#pragma unroll
      for (int j = 0; j < 4; ++j)
        kf[j] = *(const bf16x8*)(lK + (j * 16 + r15) * 512 +
                                 (((kc * 4 + lg) ^ rs7) << 4));
#pragma unroll
      for (int j = 0; j < 4; ++j) s[j] = mfma16(kf[j], qf[kc], s[j]);
    }
    __builtin_amdgcn_s_setprio(0);
    // ---- online softmax ----
    float pmax = s[0][0];
#pragma unroll
    for (int j = 0; j < 4; ++j)
#pragma unroll
      for (int r = 0; r < 4; ++r) pmax = fmaxf(pmax, s[j][r]);
    pmax = fmaxf(pmax, __shfl_xor(pmax, 16, 64));
    pmax = fmaxf(pmax, __shfl_xor(pmax, 32, 64));
    if (!__all(pmax <= mrun + 8.f)) {
      const float mn = fmaxf(mrun, pmax);
      const float scl = exp2f(mrun - mn);
      mrun = mn;
      lrun *= scl;
#pragma unroll
      for (int d = 0; d < 16; ++d) po[d] *= scl;
    }
    float psum = 0.f;
    bf16x4 pk[4];
#pragma unroll
    for (int j = 0; j < 4; ++j)
#pragma unroll
      for (int r = 0; r < 4; ++r) {
        const float pv = exp2f(s[j][r] - mrun);
        psum += pv;
        pk[j][r] = (__bf16)pv;
      }
    psum += __shfl_xor(psum, 16, 64);
    psum += __shfl_xor(psum, 32, 64);
    lrun += psum;
#pragma unroll
    for (int j = 0; j < 4; ++j)
      *(bf16x4*)(P + r15 * 128 + ((j * 32 + lg * 8) ^ (rs7 << 4))) = pk[j];

    WAIT_VM(0);
    bar();          // V(kv) resident; done reading lK
    if (kv < 15) stageK((kv + 1) * 64);

    // ---- swapped PV: O^T(256x16) += V^T(256x64) x P(16x64)^T ----
    __builtin_amdgcn_s_setprio(1);
#pragma unroll
    for (int kk = 0; kk < 2; ++kk) {
      const bf16x8 pb =
          *(const bf16x8*)(P + r15 * 128 + (((kk * 4 + lg) ^ rs7) << 4));
#pragma unroll
      for (int df = 0; df < 16; ++df) {
        const bf16x8 vf = *(const bf16x8*)(lV + (df * 16 + r15) * 128 +
                                           (((kk * 4 + lg) ^ rs7) << 4));
        po[df] = mfma16(vf, pb, po[df]);
      }
    }
    __builtin_amdgcn_s_setprio(0);
    bar();          // done reading lV
    if (kv < 15) stageV((kv + 1) * 64);
  }
  const float inv = 1.f / lrun;
  __bf16* ob = o + (((size_t)(b * 1024 + m0 + r15)) << 8);
#pragma unroll
  for (int df = 0; df < 16; ++df) {
    bf16x4 t;
#pragma unroll
    for (int r = 0; r < 4; ++r) t[r] = (__bf16)(po[df][r] * inv);
    *(bf16x4*)(ob + df * 16 + lg * 4) = t;
  }
}

// ---------------------------------------------------------------------------
// Kernel 5: proj GEMM + bias + residual (128x128 tiles, BK=64 core).
// x-read / out-write are compulsory single-use streams (256MB fp32) ->
// nontemporal to bypass L2 and keep o/weight tiles resident.
// ---------------------------------------------------------------------------
__global__ __launch_bounds__(256) void proj_gemm(
    const __bf16* __restrict__ o, const __bf16* __restrict__ wpb,
    const float* __restrict__ b_proj, const float* __restrict__ x,
    float* __restrict__ out) {
  __shared__ __align__(16) __bf16 lA[128 * 64], lB[128 * 64];
  const int nt = blockIdx.x, mt = blockIdx.y;
  const int tid = threadIdx.x, lane = tid & 63, wave = tid >> 6;
  f32x4 acc[4][4];
  gemm_core_k256(o + (size_t)mt * 128 * 256, wpb + (size_t)nt * 128 * 256,
                 lA, lB, lane, wave, acc);

  const int wm = (wave >> 1) * 64, wn = (wave & 1) * 64;
  const int r15 = lane & 15, lg = lane >> 4;
#pragma unroll
  for (int j = 0; j < 4; ++j) {
    const int c = nt * 128 + wn + j * 16 + r15;
    const float bias = b_proj[c];
#pragma unroll
    for (int i = 0; i < 4; ++i) {
      const int mbase = mt * 128 + wm + i * 16 + lg * 4;
      const int b = mbase >> 10, p = mbase & 1023;
      const size_t off = (((size_t)(b * 256 + c)) << 10) + p;
      const float* xp = x + off;
      float* op = out + off;
      f32x4 xv;
#pragma unroll
      for (int r = 0; r < 4; ++r) xv[r] = __builtin_nontemporal_load(xp + r);
      f32x4 rr = acc[i][j];
      rr = rr + xv;
      rr = rr + bias;
#pragma unroll
      for (int r = 0; r < 4; ++r) __builtin_nontemporal_store(rr[r], op + r);
    }
  }
}

// ---------------------------------------------------------------------------
// Launcher
// ---------------------------------------------------------------------------
extern "C" void kernel_launch(void* const* d_in, const int* in_sizes, int n_in,
                              void* d_out, int out_size, void* d_ws, size_t ws_size,
                              hipStream_t stream) {
  const float* x      = (const float*)d_in[0];
  // d_in[1] = t_embd (unused by reference)
  const float* gamma  = (const float*)d_in[2];
  const float* beta   = (const float*)d_in[3];
  const float* w_attn = (const float*)d_in[4];
  const float* b_attn = (const float*)d_in[5];
  const float* w_proj = (const float*)d_in[6];
  const float* b_proj = (const float*)d_in[7];
  float* out = (float*)d_out;

  char* ws = (char*)d_ws;
  __bf16* h   = (__bf16*)(ws);                          // 16MB, reused as o
  __bf16* qb  = (__bf16*)(ws + ((size_t)16 << 20));     // 16MB
  __bf16* kb  = (__bf16*)(ws + ((size_t)32 << 20));     // 16MB
  __bf16* vtb = (__bf16*)(ws + ((size_t)48 << 20));     // 16MB, [B][C][P]
  __bf16* wab = (__bf16*)(ws + ((size_t)64 << 20));     // 384KB
  __bf16* wpb = wab + 196608;                           // 128KB

  gn_fused<<<2048, 256, 0, stream>>>(x, gamma, beta, h, w_attn, w_proj, wab, wpb);
  qkv_gemm<<<1536, 256, 0, stream>>>(h, wab, b_attn, qb, kb, vtb);
  attn<<<512, 256, 73728, stream>>>(qb, kb, vtb, h /* o reuses h */);
  proj_gemm<<<dim3(2, 256), 256, 0, stream>>>(h, wpb, b_proj, x, out);
}

// Round 15
// 129.449 us; speedup vs baseline: 1.1513x; 1.0029x over previous
//
#include <hip/hip_runtime.h>
#include <hip/hip_bf16.h>
#include <stdint.h>
#include <stddef.h>

// ---------------------------------------------------------------------------
// ResAttnBlock: GroupNorm -> QKV -> full spatial attention -> proj -> residual
// B=32, C=256, S=32 (P=1024 positions), 32 groups of 8 channels.
// ---------------------------------------------------------------------------

typedef float  f32x4  __attribute__((ext_vector_type(4)));
typedef __bf16 bf16x8 __attribute__((ext_vector_type(8)));
typedef __bf16 bf16x4 __attribute__((ext_vector_type(4)));

#define DEVI static __device__ __forceinline__

DEVI f32x4 mfma16(bf16x8 a, bf16x8 b, f32x4 c) {
  return __builtin_amdgcn_mfma_f32_16x16x32_bf16(a, b, c, 0, 0, 0);
}

DEVI f32x4 zero4() { f32x4 z = {0.f, 0.f, 0.f, 0.f}; return z; }

typedef const __attribute__((address_space(1))) void* gas_cvp;
typedef __attribute__((address_space(3))) void*       las_vp;

DEVI void gl_lds16(const __bf16* g, __bf16* l) {
  __builtin_amdgcn_global_load_lds((gas_cvp)g, (las_vp)l, 16, 0, 0);
}

#define WAIT_VM(N) asm volatile("s_waitcnt vmcnt(" #N ")" ::: "memory")
DEVI void bar() {
  asm volatile("" ::: "memory");
  __builtin_amdgcn_s_barrier();
  asm volatile("" ::: "memory");
}

// ---------------------------------------------------------------------------
// Kernel 1: fused GroupNorm + weight conversion. Register-held group slice:
// thread owns 4 p-positions x 8 channels (8 x f32x4 = 32 VGPR), reads
// coalesced, reduces from regs, writes transposed bf16x8 from regs.
// NO LDS staging round-trip (R14 version staged 32KB/block).
// Blocks 0..1023: (b,g) groups. Blocks 1024..2047: weight cvt.
// ---------------------------------------------------------------------------
__global__ __launch_bounds__(256) void gn_fused(
    const float* __restrict__ x, const float* __restrict__ gamma,
    const float* __restrict__ beta, __bf16* __restrict__ h,
    const float* __restrict__ wa, const float* __restrict__ wp,
    __bf16* __restrict__ wab, __bf16* __restrict__ wpb) {
  __shared__ float redS[4], redSS[4];
  const int tid = threadIdx.x;
  if (blockIdx.x >= 1024) {            // weight-conversion blocks
    const int i = (blockIdx.x - 1024) * 256 + tid;
    if (i < 196608) wab[i] = (__bf16)wa[i];
    else wpb[i - 196608] = (__bf16)wp[i - 196608];
    return;
  }
  const int bg = blockIdx.x;           // b*32+g
  const int b = bg >> 5, g = bg & 31;
  const float* base = x + (size_t)bg * 8192 + tid * 4;
  f32x4 v[8];
  float s = 0.f, ss = 0.f;
#pragma unroll
  for (int c = 0; c < 8; ++c) {
    v[c] = *(const f32x4*)(base + c * 1024);
#pragma unroll
    for (int r = 0; r < 4; ++r) { s += v[c][r]; ss += v[c][r] * v[c][r]; }
  }
#pragma unroll
  for (int m = 1; m < 64; m <<= 1) {
    s  += __shfl_xor(s,  m, 64);
    ss += __shfl_xor(ss, m, 64);
  }
  const int lane = tid & 63, wave = tid >> 6;
  if (lane == 0) { redS[wave] = s; redSS[wave] = ss; }
  __syncthreads();
  const float S  = redS[0] + redS[1] + redS[2] + redS[3];
  const float SS = redSS[0] + redSS[1] + redSS[2] + redSS[3];
  const float mu = S * (1.f / 8192.f);
  const float rstd = rsqrtf(SS * (1.f / 8192.f) - mu * mu + 1e-5f);
  float ga[8], be[8];
#pragma unroll
  for (int j = 0; j < 8; ++j) {
    const int c = g * 8 + j;
    ga[j] = gamma[c] * rstd;
    be[j] = beta[c] - mu * ga[j];
  }
  __bf16* hb = h + ((size_t)b << 18) + (((size_t)tid * 4) << 8) + g * 8;
#pragma unroll
  for (int r = 0; r < 4; ++r) {
    bf16x8 o8;
#pragma unroll
    for (int j = 0; j < 8; ++j)
      o8[j] = (__bf16)(v[j][r] * ga[j] + be[j]);
    *(bf16x8*)(hb + (((size_t)r) << 8)) = o8;
  }
}

// ---------------------------------------------------------------------------
// Shared GEMM core: C(128x128) = A(128xK=256) * Bt(128 rows x 256)^T
// ---------------------------------------------------------------------------
DEVI void gemm_core_k256(const __bf16* __restrict__ A0, const __bf16* __restrict__ B0,
                         __bf16* lA, __bf16* lB, int lane, int wave, f32x4 acc[4][4]) {
  const int wm = (wave >> 1) * 64;
  const int wn = (wave & 1) * 64;
  const int r15 = lane & 15, lg = lane >> 4;
#pragma unroll
  for (int i = 0; i < 4; ++i)
#pragma unroll
    for (int j = 0; j < 4; ++j) acc[i][j] = zero4();

  for (int ko = 0; ko < 4; ++ko) {
#pragma unroll
    for (int it = 0; it < 4; ++it) {
      const int q = wave * 256 + it * 64 + lane;
      const int row = q >> 3, c8 = q & 7;
      const int srcoff = row * 256 + ko * 64 + ((c8 ^ (row & 7)) << 3);
      gl_lds16(A0 + srcoff, lA + (size_t)(wave * 256 + it * 64) * 8);
      gl_lds16(B0 + srcoff, lB + (size_t)(wave * 256 + it * 64) * 8);
    }
    __syncthreads();
#pragma unroll
    for (int kk = 0; kk < 2; ++kk) {
      bf16x8 af[4], bfr[4];
#pragma unroll
      for (int i = 0; i < 4; ++i) {
        const int row = wm + i * 16 + r15;
        af[i] = *(const bf16x8*)((const char*)lA + row * 128 +
                                 (((kk * 4 + lg) ^ (row & 7)) << 4));
      }
#pragma unroll
      for (int j = 0; j < 4; ++j) {
        const int row = wn + j * 16 + r15;
        bfr[j] = *(const bf16x8*)((const char*)lB + row * 128 +
                                  (((kk * 4 + lg) ^ (row & 7)) << 4));
      }
#pragma unroll
      for (int i = 0; i < 4; ++i)
#pragma unroll
        for (int j = 0; j < 4; ++j) acc[i][j] = mfma16(af[i], bfr[j], acc[i][j]);
    }
    __syncthreads();
  }
}

// ---------------------------------------------------------------------------
// Kernel 3: QKV GEMM, 128x128 tiles, XCD-affine flattened grid (R14).
// ---------------------------------------------------------------------------
__global__ __launch_bounds__(256) void qkv_gemm(
    const __bf16* __restrict__ h, const __bf16* __restrict__ wab,
    const float* __restrict__ b_attn,
    __bf16* __restrict__ q, __bf16* __restrict__ k, __bf16* __restrict__ vt) {
  __shared__ __align__(16) __bf16 lA[128 * 64], lB[128 * 64];
  const int bid = blockIdx.x;              // 0..1535
  const int xcd = bid & 7, i2 = bid >> 3;  // i2 0..191
  const int nt = i2 % 6;
  const int mt = xcd * 32 + i2 / 6;        // 32 mt per XCD
  const int tid = threadIdx.x, lane = tid & 63, wave = tid >> 6;
  f32x4 acc[4][4];
  gemm_core_k256(h + (size_t)mt * 128 * 256, wab + (size_t)nt * 128 * 256,
                 lA, lB, lane, wave, acc);

  const int wm = (wave >> 1) * 64, wn = (wave & 1) * 64;
  const int r15 = lane & 15, lg = lane >> 4;
  const int sec = nt >> 1;  // 0=q, 1=k, 2=v
  const float QS = 0.0625f * 1.44269504088896340736f;  // (1/sqrt(256))*log2(e)
#pragma unroll
  for (int j = 0; j < 4; ++j) {
    const int ng = nt * 128 + wn + j * 16 + r15;
    const float bias = b_attn[ng];
    const int c = ng & 255;
#pragma unroll
    for (int i = 0; i < 4; ++i) {
      const int mbase = mt * 128 + wm + i * 16 + lg * 4;
      if (sec == 0) {
#pragma unroll
        for (int r = 0; r < 4; ++r)
          q[(size_t)(mbase + r) * 256 + c] = (__bf16)((acc[i][j][r] + bias) * QS);
      } else if (sec == 1) {
#pragma unroll
        for (int r = 0; r < 4; ++r)
          k[(size_t)(mbase + r) * 256 + c] = (__bf16)(acc[i][j][r] + bias);
      } else {
        const int b = mbase >> 10, p = mbase & 1023;
        bf16x4 pk;
#pragma unroll
        for (int r = 0; r < 4; ++r) pk[r] = (__bf16)(acc[i][j][r] + bias);
        *(bf16x4*)(vt + (((size_t)(b * 256 + c)) << 10) + p) = pk;
      }
    }
  }
}

// ---------------------------------------------------------------------------
// Kernel 4: flash attention — R7 structure with a 2-BARRIER schedule.
// The own-vmcnt(0) for K(t+1) moves BEFORE the post-PV barrier, so that
// barrier certifies both "K(t+1) resident on all waves" and "all waves
// done reading lV" -> next iteration's QK^T starts with no top barrier.
// Race proof: lK written only after B1 (all QK^T reads done); lV written
// only after B2 (all PV reads done); residency = own-vmcnt drain + barrier.
// Everything else identical to the converged R7 design (61.5us).
// ---------------------------------------------------------------------------
__global__ __launch_bounds__(256, 2) void attn(
    const __bf16* __restrict__ q, const __bf16* __restrict__ k,
    const __bf16* __restrict__ vt, __bf16* __restrict__ o) {
  extern __shared__ __align__(16) char smem[];   // 73728 B

  const int bid = blockIdx.x;
  const int xcd = bid & 7, sub = bid >> 3;       // sub 0..63
  const int b = xcd * 4 + (sub & 3);             // same-b blocks share an XCD
  const int qt = sub >> 2;                       // 0..15
  const int tid = threadIdx.x, lane = tid & 63, wave = tid >> 6;
  const int r15 = lane & 15, lg = lane >> 4, rs7 = r15 & 7;
  const int m0 = qt * 64 + wave * 16;
  char* P = smem + 65536 + wave * 2048;

  const __bf16* kb = k  + ((size_t)b << 18);
  const __bf16* vb = vt + ((size_t)b << 18);

  const __bf16* qb = q + (((size_t)(b * 1024 + m0)) << 8);
  bf16x8 qf[8];
#pragma unroll
  for (int kc = 0; kc < 8; ++kc)
    qf[kc] = *(const bf16x8*)(qb + ((size_t)r15) * 256 + kc * 32 + lg * 8);

  f32x4 po[16];   // O^T: po[df][r] = O[q=r15][d=df*16+lg*4+r]
#pragma unroll
  for (int d = 0; d < 16; ++d) po[d] = zero4();
  float mrun = -1e30f, lrun = 0.f;

  auto stageK = [&](int n0) {
    __bf16* dst = (__bf16*)smem;
#pragma unroll
    for (int it = 0; it < 8; ++it) {
      const int qch = it * 256 + tid;            // [64 rows][32 chunks]
      const int row = qch >> 5, c32 = qch & 31;
      gl_lds16(kb + (size_t)(n0 + row) * 256 + ((c32 ^ (row & 7)) << 3),
               dst + (size_t)(it * 256 + wave * 64) * 8);
    }
  };
  auto stageV = [&](int n0) {
    __bf16* dst = (__bf16*)(smem + 32768);
#pragma unroll
    for (int it = 0; it < 8; ++it) {
      const int qch = it * 256 + tid;            // [256 rows][8 chunks]
      const int row = qch >> 3, c8 = qch & 7;
      gl_lds16(vb + ((size_t)row << 10) + n0 + ((c8 ^ (row & 7)) << 3),
               dst + (size_t)(it * 256 + wave * 64) * 8);
    }
  };

  stageK(0);
  stageV(0);
  WAIT_VM(8);     // own K(0) landed (V(0)'s 8 still in flight)
  bar();          // K(0) resident on all waves

  const char* lK = (const char*)smem;
  const char* lV = (const char*)smem + 32768;

  for (int kv = 0; kv < 16; ++kv) {
    // ---- swapped QK^T: S^T(64x16) = K(64x256) x Q(16x256)^T ----
    // lK residency guaranteed by prologue / previous iteration's B2.
    f32x4 s[4];
#pragma unroll
    for (int j = 0; j < 4; ++j) s[j] = zero4();
    __builtin_amdgcn_s_setprio(1);
#pragma unroll
    for (int kc = 0; kc < 8; ++kc) {
      bf16x8 kf[4];
#pragma unroll
      for (int j = 0; j < 4; ++j)
        kf[j] = *(const bf16x8*)(lK + (j * 16 + r15) * 512 +
                                 (((kc * 4 + lg) ^ rs7) << 4));
#pragma unroll
      for (int j = 0; j < 4; ++j) s[j] = mfma16(kf[j], qf[kc], s[j]);
    }
    __builtin_amdgcn_s_setprio(0);
    // ---- online softmax ----
    float pmax = s[0][0];
#pragma unroll
    for (int j = 0; j < 4; ++j)
#pragma unroll
      for (int r = 0; r < 4; ++r) pmax = fmaxf(pmax, s[j][r]);
    pmax = fmaxf(pmax, __shfl_xor(pmax, 16, 64));
    pmax = fmaxf(pmax, __shfl_xor(pmax, 32, 64));
    if (!__all(pmax <= mrun + 8.f)) {
      const float mn = fmaxf(mrun, pmax);
      const float scl = exp2f(mrun - mn);
      mrun = mn;
      lrun *= scl;
#pragma unroll
      for (int d = 0; d < 16; ++d) po[d] *= scl;
    }
    float psum = 0.f;
    bf16x4 pk[4];
#pragma unroll
    for (int j = 0; j < 4; ++j)
#pragma unroll
      for (int r = 0; r < 4; ++r) {
        const float pv = exp2f(s[j][r] - mrun);
        psum += pv;
        pk[j][r] = (__bf16)pv;
      }
    psum += __shfl_xor(psum, 16, 64);
    psum += __shfl_xor(psum, 32, 64);
    lrun += psum;
#pragma unroll
    for (int j = 0; j < 4; ++j)
      *(bf16x4*)(P + r15 * 128 + ((j * 32 + lg * 8) ^ (rs7 << 4))) = pk[j];

    WAIT_VM(0);     // own V(kv) writes landed (K(kv+1) not yet issued)
    bar();          // B1: V(kv) resident all-waves; all waves done reading lK
    if (kv < 15) stageK((kv + 1) * 64);   // overwrite lK, hides under PV

    // ---- swapped PV: O^T(256x16) += V^T(256x64) x P(16x64)^T ----
    __builtin_amdgcn_s_setprio(1);
#pragma unroll
    for (int kk = 0; kk < 2; ++kk) {
      const bf16x8 pb =
          *(const bf16x8*)(P + r15 * 128 + (((kk * 4 + lg) ^ rs7) << 4));
#pragma unroll
      for (int df = 0; df < 16; ++df) {
        const bf16x8 vf = *(const bf16x8*)(lV + (df * 16 + r15) * 128 +
                                           (((kk * 4 + lg) ^ rs7) << 4));
        po[df] = mfma16(vf, pb, po[df]);
      }
    }
    __builtin_amdgcn_s_setprio(0);
    WAIT_VM(0);     // own K(kv+1) writes landed (mostly covered by PV)
    bar();          // B2: K(kv+1) resident all-waves; all done reading lV
    if (kv < 15) stageV((kv + 1) * 64);   // overwrite lV, hides under QK^T
  }
  const float inv = 1.f / lrun;
  __bf16* ob = o + (((size_t)(b * 1024 + m0 + r15)) << 8);
#pragma unroll
  for (int df = 0; df < 16; ++df) {
    bf16x4 t;
#pragma unroll
    for (int r = 0; r < 4; ++r) t[r] = (__bf16)(po[df][r] * inv);
    *(bf16x4*)(ob + df * 16 + lg * 4) = t;
  }
}

// ---------------------------------------------------------------------------
// Kernel 5: proj GEMM + bias + residual; nontemporal x/out streams (R14).
// ---------------------------------------------------------------------------
__global__ __launch_bounds__(256) void proj_gemm(
    const __bf16* __restrict__ o, const __bf16* __restrict__ wpb,
    const float* __restrict__ b_proj, const float* __restrict__ x,
    float* __restrict__ out) {
  __shared__ __align__(16) __bf16 lA[128 * 64], lB[128 * 64];
  const int nt = blockIdx.x, mt = blockIdx.y;
  const int tid = threadIdx.x, lane = tid & 63, wave = tid >> 6;
  f32x4 acc[4][4];
  gemm_core_k256(o + (size_t)mt * 128 * 256, wpb + (size_t)nt * 128 * 256,
                 lA, lB, lane, wave, acc);

  const int wm = (wave >> 1) * 64, wn = (wave & 1) * 64;
  const int r15 = lane & 15, lg = lane >> 4;
#pragma unroll
  for (int j = 0; j < 4; ++j) {
    const int c = nt * 128 + wn + j * 16 + r15;
    const float bias = b_proj[c];
#pragma unroll
    for (int i = 0; i < 4; ++i) {
      const int mbase = mt * 128 + wm + i * 16 + lg * 4;
      const int b = mbase >> 10, p = mbase & 1023;
      const size_t off = (((size_t)(b * 256 + c)) << 10) + p;
      const float* xp = x + off;
      float* op = out + off;
      f32x4 xv;
#pragma unroll
      for (int r = 0; r < 4; ++r) xv[r] = __builtin_nontemporal_load(xp + r);
      f32x4 rr = acc[i][j];
      rr = rr + xv;
      rr = rr + bias;
#pragma unroll
      for (int r = 0; r < 4; ++r) __builtin_nontemporal_store(rr[r], op + r);
    }
  }
}

// ---------------------------------------------------------------------------
// Launcher
// ---------------------------------------------------------------------------
extern "C" void kernel_launch(void* const* d_in, const int* in_sizes, int n_in,
                              void* d_out, int out_size, void* d_ws, size_t ws_size,
                              hipStream_t stream) {
  const float* x      = (const float*)d_in[0];
  // d_in[1] = t_embd (unused by reference)
  const float* gamma  = (const float*)d_in[2];
  const float* beta   = (const float*)d_in[3];
  const float* w_attn = (const float*)d_in[4];
  const float* b_attn = (const float*)d_in[5];
  const float* w_proj = (const float*)d_in[6];
  const float* b_proj = (const float*)d_in[7];
  float* out = (float*)d_out;

  char* ws = (char*)d_ws;
  __bf16* h   = (__bf16*)(ws);                          // 16MB, reused as o
  __bf16* qb  = (__bf16*)(ws + ((size_t)16 << 20));     // 16MB
  __bf16* kb  = (__bf16*)(ws + ((size_t)32 << 20));     // 16MB
  __bf16* vtb = (__bf16*)(ws + ((size_t)48 << 20));     // 16MB, [B][C][P]
  __bf16* wab = (__bf16*)(ws + ((size_t)64 << 20));     // 384KB
  __bf16* wpb = wab + 196608;                           // 128KB

  gn_fused<<<2048, 256, 0, stream>>>(x, gamma, beta, h, w_attn, w_proj, wab, wpb);
  qkv_gemm<<<1536, 256, 0, stream>>>(h, wab, b_attn, qb, kb, vtb);
  attn<<<512, 256, 73728, stream>>>(qb, kb, vtb, h /* o reuses h */);
  proj_gemm<<<dim3(2, 256), 256, 0, stream>>>(h, wpb, b_proj, x, out);
}